// Round 15
// baseline (434.604 us; speedup 1.0000x reference)
//
#include <hip/hip_runtime.h>
#include <hip/hip_bf16.h>
#include <stdint.h>

typedef __attribute__((ext_vector_type(8))) short short8;
typedef __attribute__((ext_vector_type(4))) float f32x4;

#define M_DIM 8192
#define N_DIM 4096
#define K_DIM 4096
#define BM 256
#define BN 256
#define BK 64

static __device__ __forceinline__ unsigned short f32_to_bf16(float f) {
  union { float f; unsigned int u; } v; v.f = f;
  unsigned int u = v.u;
  u += 0x7fffu + ((u >> 16) & 1u);   // round-to-nearest-even
  return (unsigned short)(u >> 16);
}

// ------- prep: dequant ONLY (x-cast folded into GEMM A-staging, R15) -------
__global__ void prep_kernel(const int* __restrict__ qw,
                            const float* __restrict__ scale,
                            const float* __restrict__ zero,
                            unsigned short* __restrict__ W) {
  int idx = blockIdx.x * blockDim.x + threadIdx.x;   // n*128 + c
  int n = idx >> 7;
  int c = idx & 127;
  unsigned int w[8];
#pragma unroll
  for (int k = 0; k < 8; ++k)
    w[k] = (unsigned int)qw[(size_t)k * (N_DIM * 128) + idx];
  int wp = c >> 5, t = c & 31;
#pragma unroll
  for (int s = 0; s < 4; ++s) {
    int r = s ^ 3;
    unsigned int by[8];
#pragma unroll
    for (int k = 0; k < 8; ++k) by[k] = (w[k] >> (8 * r)) & 0xffu;
    int ibase = wp * 1024 + s * 256 + t * 8;
    int g = ibase >> 7;
    float sc = scale[n * 32 + g];
    float zp = zero[n * 32 + g] * 16.0f;
    short8 o;
#pragma unroll
    for (int u = 0; u < 8; ++u) {
      unsigned int q = 0;
#pragma unroll
      for (int k = 0; k < 8; ++k)
        q |= ((by[k] >> (7 - u)) & 1u) << (7 - k);
      o[u] = (short)f32_to_bf16(sc * ((float)q - zp));
    }
    *reinterpret_cast<short8*>(&W[(size_t)n * K_DIM + ibase]) = o;
  }
}

// ---- 256x256 8-region bf16 GEMM, R8 schedule + f32-A reg-staging (R15) ----
// C[M][N] = x[M][K](f32) * B[N][K]^T + bias. 8 waves (2Mx4N), wave out 128x64.
// B path: global_load_lds, unchanged. A path: 4x float4 loads from x (f32),
// 16x cvt, 2x ds_write_b128 (write-side swizzle; content identical to R14).
// LEDGER (re-derived for mixed staging):
//  * A f32 loads are consumed by cvt in-region -> leave vmcnt FIFO early, so
//    hand vmcnt counts see only B pairs: r8 entry must be vmcnt(0) (drains
//    B(0,1)@r6 read at next r1); r3/r5/r7 vmcnt(2) drain B(1,0)/B(1,1)/B(0,0)
//    exactly one barrier before their reads at r4/r6/r8. ✓
//  * ds_write visibility: entry lgkmcnt(0) (R8 A/B: perf-neutral) ->
//    write@s -> writer drain s+1 entry -> barrier s+2 -> read s+3 for all
//    A-edges: A(1,1)@r3->r6, A(0,0)@r5->r8, A(0,1)@r6... r7->next r2,
//    A(1,0)@r8->next r4; peel A(1,1)@p3->p6. ✓
//  * Prologue: lgkm(0)+vmcnt(0) BEFORE the barrier (R5/R12 lesson: drain ->
//    barrier -> read, per-wave counters don't cover other waves' stages).
// A-write bank pattern = same 8-slot-XOR family as the measured-0-conflict
// read pattern (2 lanes per 16B slot per 16-lane phase).

#define VMCNT2 asm volatile("s_waitcnt vmcnt(2)" ::: "memory")
#define VMCNT0 asm volatile("s_waitcnt vmcnt(0)" ::: "memory")
#define LGKM0  asm volatile("s_waitcnt lgkmcnt(0)" ::: "memory")
#define NOOP ((void)0)
#define SB0 __builtin_amdgcn_sched_barrier(0)

// B stage: one 128x64 half (16KB), 2x global_load_lds, source-inverse swizzle
#define STG_B(BUF, H, KT) do {                                                 \
  const unsigned short* sb_ = Bg + ((size_t)(n0 + (H)*128) * K_DIM + (KT) * 64); \
  __builtin_amdgcn_global_load_lds(                                            \
      (const __attribute__((address_space(1))) void*)(sb_ + s_off0),           \
      (__attribute__((address_space(3))) void*)(smem + 65536 +                 \
          ((BUF)*2 + (H)) * 16384 + wslot), 16, 0, 0);                         \
  __builtin_amdgcn_global_load_lds(                                            \
      (const __attribute__((address_space(1))) void*)(sb_ + s_off1),           \
      (__attribute__((address_space(3))) void*)(smem + 65536 +                 \
          ((BUF)*2 + (H)) * 16384 + 8192 + wslot), 16, 0, 0);                  \
} while (0)

// A stage: reg-staged f32 -> bf16 -> swizzled ds_write (one 128x64 half)
#define STG_A(BUF, H, KT) do {                                                 \
  const float* xs_ = Xf + a_src + ((size_t)(m0 + (H)*128) * K_DIM + (KT)*64);  \
  float4 f0_ = *(const float4*)(xs_);                                          \
  float4 f1_ = *(const float4*)(xs_ + 4);                                      \
  float4 f2_ = *(const float4*)(xs_ + 8);                                      \
  float4 f3_ = *(const float4*)(xs_ + 12);                                     \
  short8 w0_, w1_;                                                             \
  w0_[0] = (short)f32_to_bf16(f0_.x); w0_[1] = (short)f32_to_bf16(f0_.y);      \
  w0_[2] = (short)f32_to_bf16(f0_.z); w0_[3] = (short)f32_to_bf16(f0_.w);      \
  w0_[4] = (short)f32_to_bf16(f1_.x); w0_[5] = (short)f32_to_bf16(f1_.y);      \
  w0_[6] = (short)f32_to_bf16(f1_.z); w0_[7] = (short)f32_to_bf16(f1_.w);      \
  w1_[0] = (short)f32_to_bf16(f2_.x); w1_[1] = (short)f32_to_bf16(f2_.y);      \
  w1_[2] = (short)f32_to_bf16(f2_.z); w1_[3] = (short)f32_to_bf16(f2_.w);      \
  w1_[4] = (short)f32_to_bf16(f3_.x); w1_[5] = (short)f32_to_bf16(f3_.y);      \
  w1_[6] = (short)f32_to_bf16(f3_.z); w1_[7] = (short)f32_to_bf16(f3_.w);      \
  *(short8*)(smem + ((BUF)*2 + (H)) * 16384 + aw_off0) = w0_;                  \
  *(short8*)(smem + ((BUF)*2 + (H)) * 16384 + aw_off1) = w1_;                  \
} while (0)

// reads for ONE k-slot (KK literal): 4 A-frags or 2 B-frags
#define LA(BUF, QM, KK) do {                                                   \
  _Pragma("unroll") for (int mf_ = 0; mf_ < 4; ++mf_)                          \
    a_[mf_][KK] = *(const short8*)(smem + ((KK) ? a_off1 : a_off0) +           \
        (((BUF)*2 + (QM)) * 16384 + mf_ * 2048));                              \
} while (0)
#define LB(BUF, QN, KK) do {                                                   \
  _Pragma("unroll") for (int nf_ = 0; nf_ < 2; ++nf_)                          \
    b_[nf_][KK] = *(const short8*)(smem + ((KK) ? b_off1 : b_off0) +           \
        (((BUF)*2 + (QN)) * 16384 + nf_ * 2048));                              \
} while (0)

#define MFMA_KK(QM, QN, KK)                                                    \
  _Pragma("unroll") for (int mf_ = 0; mf_ < 4; ++mf_)                          \
    _Pragma("unroll") for (int nf_ = 0; nf_ < 2; ++nf_)                        \
      acc[QM][QN][mf_][nf_] = __builtin_amdgcn_mfma_f32_16x16x32_bf16(         \
          a_[mf_][KK], b_[nf_][KK], acc[QM][QN][mf_][nf_], 0, 0, 0)

// one region; RD0/RD1 load operands for the NEXT region's MFMAs.
#define REGION(QM, QN, RD0, RD1, STAGE, WAITV) do {                            \
  __builtin_amdgcn_s_barrier();                                                \
  WAITV;                                                                       \
  LGKM0;                                                                       \
  SB0;                                                                         \
  __builtin_amdgcn_s_setprio(1);                                               \
  STAGE;                                                                       \
  MFMA_KK(QM, QN, 0);                                                          \
  RD0;                                                                         \
  SB0;                                                                         \
  MFMA_KK(QM, QN, 1);                                                          \
  RD1;                                                                         \
  SB0;                                                                         \
  __builtin_amdgcn_s_setprio(0);                                               \
} while (0)

__global__ __launch_bounds__(512, 2) void gemm_kernel(
    const float* __restrict__ Xf,            // x [M][K] f32
    const unsigned short* __restrict__ Bg,   // Wb [N][K] bf16
    const float* __restrict__ bias,
    float* __restrict__ C) {
  __shared__ __align__(16) char smem[131072];   // A: [0,64K), B: [64K,128K)

  // XCD-aware bijective swizzle: 512 blocks % 8 == 0
  int bid = blockIdx.x;
  int cpx = gridDim.x >> 3;
  int swz = (bid & 7) * cpx + (bid >> 3);
  int tm = swz >> 4;                 // 32 M-tiles
  int tn = swz & 15;                 // 16 N-tiles
  int m0 = tm * BM, n0 = tn * BN;

  int tid = threadIdx.x;
  int lane = tid & 63;
  int wid = tid >> 6;                // 8 waves
  int wr = wid >> 2, wc = wid & 3;   // 2 x 4

  // hoisted read addressing (R4, validated)
  const int xorv = (lane & 7) << 4;
  const int hi4 = (lane >> 4) << 4;
  const int wrbase = wr * 64 + (lane & 15);
  const int wcbase = wc * 32 + (lane & 15);
  const int a_off0 = (wrbase << 7) + (hi4 ^ xorv);
  const int a_off1 = (wrbase << 7) + ((64 | hi4) ^ xorv);
  const int b_off0 = 65536 + (wcbase << 7) + (hi4 ^ xorv);
  const int b_off1 = 65536 + (wcbase << 7) + ((64 | hi4) ^ xorv);
  // B stage lane addressing (gld_lds, linear dest + inverse-swizzled src)
  const int wslot = wid << 10;
  const int s_lr0 = tid >> 3, s_lr1 = 64 + (tid >> 3);
  const int s_off0 = s_lr0 * K_DIM + (((tid & 7) ^ (s_lr0 & 7)) << 3);
  const int s_off1 = s_lr1 * K_DIM + (((tid & 7) ^ (s_lr1 & 7)) << 3);
  // A stage lane addressing: row = tid>>2 (4 lanes/row, 256B coalesced src),
  // slot-pair = tid&3; write-side swizzle slot ^= (row&7)
  const int aw_row = tid >> 2;
  const int aq = tid & 3;
  const size_t a_src = (size_t)aw_row * K_DIM + aq * 16;
  const int aw_off0 = (aw_row << 7) + (((aq * 2) ^ (aw_row & 7)) << 4);
  const int aw_off1 = (aw_row << 7) + (((aq * 2 + 1) ^ (aw_row & 7)) << 4);

  short8 a_[4][2], b_[2][2];
  f32x4 acc[2][2][4][2];
#pragma unroll
  for (int i = 0; i < 2; ++i)
#pragma unroll
    for (int j = 0; j < 2; ++j)
#pragma unroll
      for (int mf = 0; mf < 4; ++mf)
#pragma unroll
        for (int nf = 0; nf < 2; ++nf) acc[i][j][mf][nf] = (f32x4){0.f, 0.f, 0.f, 0.f};

  // prologue: buf0 <- kt0 (B00,A00,B01,A01), buf1 A10 <- kt1.
  // vmcnt(0)+lgkm(0) BEFORE the barrier: every wave's stages (B gld_lds and
  // A ds_writes) drained, then barrier, THEN cross-slot ds_reads.
  STG_B(0, 0, 0); STG_A(0, 0, 0); STG_B(0, 1, 0); STG_A(0, 1, 0);
  STG_A(1, 0, 1);
  VMCNT0;
  LGKM0;
  SB0;
  __builtin_amdgcn_s_barrier();
  LA(0, 0, 0); LB(0, 0, 0); LA(0, 0, 1); LB(0, 0, 1);  // reads for region 1

  for (int t = 0; t < 31; ++t) {
    const int kt1 = 2 * t + 1;     // buf0 = kt1-1, buf1 = kt1
    REGION(0, 0, LB(0,1,0),            LB(0,1,1),            STG_B(1,0,kt1),   VMCNT2);
    REGION(0, 1, LA(0,1,0),            LA(0,1,1),            STG_B(1,1,kt1),   VMCNT2);
    REGION(1, 1, LB(0,0,0),            LB(0,0,1),            STG_A(1,1,kt1),   VMCNT2);
    REGION(1, 0, LA(1,0,0); LB(1,0,0), LA(1,0,1); LB(1,0,1), STG_B(0,0,kt1+1), VMCNT2);
    REGION(0, 0, LB(1,1,0),            LB(1,1,1),            STG_A(0,0,kt1+1), VMCNT2);
    REGION(0, 1, LA(1,1,0),            LA(1,1,1),            STG_B(0,1,kt1+1), VMCNT2);
    REGION(1, 1, LB(1,0,0),            LB(1,0,1),            STG_A(0,1,kt1+1), VMCNT2);
    REGION(1, 0, LA(0,0,0); LB(0,0,0), LA(0,0,1); LB(0,0,1), STG_A(1,0,kt1+2), VMCNT0);
  }
  // peeled final iteration: buf0 = 62, buf1 = 63; no OOB stages.
  REGION(0, 0, LB(0,1,0),            LB(0,1,1),            STG_B(1,0,63), VMCNT2);
  REGION(0, 1, LA(0,1,0),            LA(0,1,1),            STG_B(1,1,63), VMCNT2);
  REGION(1, 1, LB(0,0,0),            LB(0,0,1),            STG_A(1,1,63), VMCNT2);
  REGION(1, 0, LA(1,0,0); LB(1,0,0), LA(1,0,1); LB(1,0,1), NOOP,          VMCNT2);
  REGION(0, 0, LB(1,1,0),            LB(1,1,1),            NOOP,          VMCNT0);
  REGION(0, 1, LA(1,1,0),            LA(1,1,1),            NOOP,          NOOP);
  REGION(1, 1, LB(1,0,0),            LB(1,0,1),            NOOP,          NOOP);
  REGION(1, 0, NOOP,                 NOOP,                 NOOP,          NOOP);

  // epilogue: C/D layout col=lane&15, row=(lane>>4)*4+j
#pragma unroll
  for (int qn = 0; qn < 2; ++qn)
#pragma unroll
    for (int nf = 0; nf < 2; ++nf) {
      int gcol = n0 + qn * 128 + wc * 32 + nf * 16 + (lane & 15);
      float bv = bias[gcol];
#pragma unroll
      for (int qm = 0; qm < 2; ++qm)
#pragma unroll
        for (int mf = 0; mf < 4; ++mf) {
          int grow = m0 + qm * 128 + wr * 64 + mf * 16 + ((lane >> 4) << 2);
          f32x4 v = acc[qm][qn][mf][nf];
#pragma unroll
          for (int j = 0; j < 4; ++j)
            C[(size_t)(grow + j) * N_DIM + gcol] = v[j] + bv;
        }
    }
}

extern "C" void kernel_launch(void* const* d_in, const int* in_sizes, int n_in,
                              void* d_out, int out_size, void* d_ws, size_t ws_size,
                              hipStream_t stream) {
  const float* x       = (const float*)d_in[0];
  const int*   qweight = (const int*)d_in[1];
  const float* scale   = (const float*)d_in[2];
  const float* zero    = (const float*)d_in[3];
  const float* bias    = (const float*)d_in[4];
  float* out = (float*)d_out;

  unsigned short* Wb = (unsigned short*)d_ws;                    // 32 MB

  prep_kernel<<<2048, 256, 0, stream>>>(qweight, scale, zero, Wb);
  gemm_kernel<<<(M_DIM / BM) * (N_DIM / BN), 512, 0, stream>>>(x, Wb, bias, out);
}

// Round 16
// 409.626 us; speedup vs baseline: 1.0610x; 1.0610x over previous
//
#include <hip/hip_runtime.h>
#include <hip/hip_bf16.h>
#include <stdint.h>

typedef __attribute__((ext_vector_type(8))) short short8;
typedef __attribute__((ext_vector_type(4))) float f32x4;

#define M_DIM 8192
#define N_DIM 4096
#define K_DIM 4096
#define BM 256
#define BN 256
#define BK 64

static __device__ __forceinline__ unsigned short f32_to_bf16(float f) {
  union { float f; unsigned int u; } v; v.f = f;
  unsigned int u = v.u;
  u += 0x7fffu + ((u >> 16) & 1u);   // round-to-nearest-even
  return (unsigned short)(u >> 16);
}

// ------- prep: dequant ONLY (x-cast folded into GEMM A-staging) -------
__global__ void prep_kernel(const int* __restrict__ qw,
                            const float* __restrict__ scale,
                            const float* __restrict__ zero,
                            unsigned short* __restrict__ W) {
  int idx = blockIdx.x * blockDim.x + threadIdx.x;   // n*128 + c
  int n = idx >> 7;
  int c = idx & 127;
  unsigned int w[8];
#pragma unroll
  for (int k = 0; k < 8; ++k)
    w[k] = (unsigned int)qw[(size_t)k * (N_DIM * 128) + idx];
  int wp = c >> 5, t = c & 31;
#pragma unroll
  for (int s = 0; s < 4; ++s) {
    int r = s ^ 3;
    unsigned int by[8];
#pragma unroll
    for (int k = 0; k < 8; ++k) by[k] = (w[k] >> (8 * r)) & 0xffu;
    int ibase = wp * 1024 + s * 256 + t * 8;
    int g = ibase >> 7;
    float sc = scale[n * 32 + g];
    float zp = zero[n * 32 + g] * 16.0f;
    short8 o;
#pragma unroll
    for (int u = 0; u < 8; ++u) {
      unsigned int q = 0;
#pragma unroll
      for (int k = 0; k < 8; ++k)
        q |= ((by[k] >> (7 - u)) & 1u) << (7 - k);
      o[u] = (short)f32_to_bf16(sc * ((float)q - zp));
    }
    *reinterpret_cast<short8*>(&W[(size_t)n * K_DIM + ibase]) = o;
  }
}

// ---- 256x256 8-region GEMM, fused x-cast with T14 async A-staging (R16) ----
// C = x(f32) * Wb^T + bias. R14 schedule; A path split: A_ISSUE (4x float4 ->
// regs) runs 2 REGIONS BEFORE A_WRITE (16 cvt + 2 swizzled ds_write_b128).
// Two reg sets (aA_/aB_, 32 VGPR, static names — rule #20).
//   issues:  r3->#2(A00',kt1+1,SetB)  r5->#3(A01',SetA)  r6->#4(A10'',SetB)
//            r8->#1'(A11'',kt1+2,SetA)   [prologue seeds #1 into SetA]
//   writes:  r3:(1,1)<-#1  r5:(0,0)<-#2  r7:(0,1)<-#3  r8:(1,0)<-#4
// A_WRITE precedes A_ISSUE in-region: a conservative compiler vmcnt before
// the cvt sees an already-drained FIFO (entry waits drain the consumed set).
// ENTRY WAITS (full-FIFO derivation; every drained item is >=2 regions old):
//   r1 -, r2 -, r3 vmcnt(2)[A#1+B(1,0)], r4 vmcnt(4)[B(1,1)],
//   r5 vmcnt(2)[A#2], r6 -, r7 vmcnt(6)[B(0,0)'+A#3], r8 vmcnt(0)[B(0,1)'+A#4]
// B edges all drain->barrier->read with >=1 interposed barrier; ds_write
// edges: write@s -> writer LGKM0@s+1 entry -> s+2 barrier -> read@s+3
// (R15-verified-correct edge set). SB0 between B-stage and A-ops pins FIFO
// order (drain counts depend on issue order). Peel: p4 entry vmcnt(0)
// (steady r4 drain doesn't cover B(1,1,63) there).

#define VMCNT2 asm volatile("s_waitcnt vmcnt(2)" ::: "memory")
#define VMCNT4 asm volatile("s_waitcnt vmcnt(4)" ::: "memory")
#define VMCNT6 asm volatile("s_waitcnt vmcnt(6)" ::: "memory")
#define VMCNT0 asm volatile("s_waitcnt vmcnt(0)" ::: "memory")
#define LGKM0  asm volatile("s_waitcnt lgkmcnt(0)" ::: "memory")
#define NOOP ((void)0)
#define SB0 __builtin_amdgcn_sched_barrier(0)

// B stage: one 128x64 half (16KB), 2x global_load_lds, source-inverse swizzle
#define STG_B(BUF, H, KT) do {                                                 \
  const unsigned short* sb_ = Bg + ((size_t)(n0 + (H)*128) * K_DIM + (KT) * 64); \
  __builtin_amdgcn_global_load_lds(                                            \
      (const __attribute__((address_space(1))) void*)(sb_ + s_off0),           \
      (__attribute__((address_space(3))) void*)(smem + 65536 +                 \
          ((BUF)*2 + (H)) * 16384 + wslot), 16, 0, 0);                         \
  __builtin_amdgcn_global_load_lds(                                            \
      (const __attribute__((address_space(1))) void*)(sb_ + s_off1),           \
      (__attribute__((address_space(3))) void*)(smem + 65536 +                 \
          ((BUF)*2 + (H)) * 16384 + 8192 + wslot), 16, 0, 0);                  \
} while (0)

// A issue: 4x float4 from x (f32) into a register set (fire now, use 2 regions later)
#define A_ISSUE(SET, H, KT) do {                                               \
  const float* xs_ = Xf + a_src + ((size_t)(m0 + (H)*128) * K_DIM + (KT)*64);  \
  SET[0] = *(const float4*)(xs_);                                              \
  SET[1] = *(const float4*)(xs_ + 4);                                          \
  SET[2] = *(const float4*)(xs_ + 8);                                          \
  SET[3] = *(const float4*)(xs_ + 12);                                         \
} while (0)

// A write: cvt set -> bf16, swizzled ds_write into LDS A region
#define A_WRITE(SET, BUF, H) do {                                              \
  short8 w0_, w1_;                                                             \
  w0_[0] = (short)f32_to_bf16(SET[0].x); w0_[1] = (short)f32_to_bf16(SET[0].y);\
  w0_[2] = (short)f32_to_bf16(SET[0].z); w0_[3] = (short)f32_to_bf16(SET[0].w);\
  w0_[4] = (short)f32_to_bf16(SET[1].x); w0_[5] = (short)f32_to_bf16(SET[1].y);\
  w0_[6] = (short)f32_to_bf16(SET[1].z); w0_[7] = (short)f32_to_bf16(SET[1].w);\
  w1_[0] = (short)f32_to_bf16(SET[2].x); w1_[1] = (short)f32_to_bf16(SET[2].y);\
  w1_[2] = (short)f32_to_bf16(SET[2].z); w1_[3] = (short)f32_to_bf16(SET[2].w);\
  w1_[4] = (short)f32_to_bf16(SET[3].x); w1_[5] = (short)f32_to_bf16(SET[3].y);\
  w1_[6] = (short)f32_to_bf16(SET[3].z); w1_[7] = (short)f32_to_bf16(SET[3].w);\
  *(short8*)(smem + ((BUF)*2 + (H)) * 16384 + aw_off0) = w0_;                  \
  *(short8*)(smem + ((BUF)*2 + (H)) * 16384 + aw_off1) = w1_;                  \
} while (0)

// reads for ONE k-slot (KK literal): 4 A-frags or 2 B-frags
#define LA(BUF, QM, KK) do {                                                   \
  _Pragma("unroll") for (int mf_ = 0; mf_ < 4; ++mf_)                          \
    a_[mf_][KK] = *(const short8*)(smem + ((KK) ? a_off1 : a_off0) +           \
        (((BUF)*2 + (QM)) * 16384 + mf_ * 2048));                              \
} while (0)
#define LB(BUF, QN, KK) do {                                                   \
  _Pragma("unroll") for (int nf_ = 0; nf_ < 2; ++nf_)                          \
    b_[nf_][KK] = *(const short8*)(smem + ((KK) ? b_off1 : b_off0) +           \
        (((BUF)*2 + (QN)) * 16384 + nf_ * 2048));                              \
} while (0)

#define MFMA_KK(QM, QN, KK)                                                    \
  _Pragma("unroll") for (int mf_ = 0; mf_ < 4; ++mf_)                          \
    _Pragma("unroll") for (int nf_ = 0; nf_ < 2; ++nf_)                        \
      acc[QM][QN][mf_][nf_] = __builtin_amdgcn_mfma_f32_16x16x32_bf16(         \
          a_[mf_][KK], b_[nf_][KK], acc[QM][QN][mf_][nf_], 0, 0, 0)

// region: bar; WAITV; LGKM0; SB0; prio1; STAGE; SB0; MFMA0; RD0; SB0;
//         MFMA1; RD1; SB0; prio0.
#define REGION(QM, QN, RD0, RD1, STAGE, WAITV) do {                            \
  __builtin_amdgcn_s_barrier();                                                \
  WAITV;                                                                       \
  LGKM0;                                                                       \
  SB0;                                                                         \
  __builtin_amdgcn_s_setprio(1);                                               \
  STAGE;                                                                       \
  SB0;                                                                         \
  MFMA_KK(QM, QN, 0);                                                          \
  RD0;                                                                         \
  SB0;                                                                         \
  MFMA_KK(QM, QN, 1);                                                          \
  RD1;                                                                         \
  SB0;                                                                         \
  __builtin_amdgcn_s_setprio(0);                                               \
} while (0)

__global__ __launch_bounds__(512, 2) void gemm_kernel(
    const float* __restrict__ Xf,            // x [M][K] f32
    const unsigned short* __restrict__ Bg,   // Wb [N][K] bf16
    const float* __restrict__ bias,
    float* __restrict__ C) {
  __shared__ __align__(16) char smem[131072];   // A: [0,64K), B: [64K,128K)

  // XCD-aware bijective swizzle: 512 blocks % 8 == 0
  int bid = blockIdx.x;
  int cpx = gridDim.x >> 3;
  int swz = (bid & 7) * cpx + (bid >> 3);
  int tm = swz >> 4;                 // 32 M-tiles
  int tn = swz & 15;                 // 16 N-tiles
  int m0 = tm * BM, n0 = tn * BN;

  int tid = threadIdx.x;
  int lane = tid & 63;
  int wid = tid >> 6;                // 8 waves
  int wr = wid >> 2, wc = wid & 3;   // 2 x 4

  // hoisted read addressing (R4, validated)
  const int xorv = (lane & 7) << 4;
  const int hi4 = (lane >> 4) << 4;
  const int wrbase = wr * 64 + (lane & 15);
  const int wcbase = wc * 32 + (lane & 15);
  const int a_off0 = (wrbase << 7) + (hi4 ^ xorv);
  const int a_off1 = (wrbase << 7) + ((64 | hi4) ^ xorv);
  const int b_off0 = 65536 + (wcbase << 7) + (hi4 ^ xorv);
  const int b_off1 = 65536 + (wcbase << 7) + ((64 | hi4) ^ xorv);
  // B stage lane addressing (gld_lds, linear dest + inverse-swizzled src)
  const int wslot = wid << 10;
  const int s_lr0 = tid >> 3, s_lr1 = 64 + (tid >> 3);
  const int s_off0 = s_lr0 * K_DIM + (((tid & 7) ^ (s_lr0 & 7)) << 3);
  const int s_off1 = s_lr1 * K_DIM + (((tid & 7) ^ (s_lr1 & 7)) << 3);
  // A stage lane addressing: row = tid>>2 (4 lanes/row, 256B coalesced src),
  // slot-pair = tid&3; write-side swizzle slot ^= (row&7) (R15-verified)
  const int aw_row = tid >> 2;
  const int aq = tid & 3;
  const size_t a_src = (size_t)aw_row * K_DIM + aq * 16;
  const int aw_off0 = (aw_row << 7) + (((aq * 2) ^ (aw_row & 7)) << 4);
  const int aw_off1 = (aw_row << 7) + (((aq * 2 + 1) ^ (aw_row & 7)) << 4);

  short8 a_[4][2], b_[2][2];
  float4 aA_[4], aB_[4];             // A-issue ping-pong sets (static names)
  f32x4 acc[2][2][4][2];
#pragma unroll
  for (int i = 0; i < 2; ++i)
#pragma unroll
    for (int j = 0; j < 2; ++j)
#pragma unroll
      for (int mf = 0; mf < 4; ++mf)
#pragma unroll
        for (int nf = 0; nf < 2; ++nf) acc[i][j][mf][nf] = (f32x4){0.f, 0.f, 0.f, 0.f};

  // prologue: B(0,0),B(0,1) via gld_lds; A(0,0),A(0,1),A(1,0) reg-staged with
  // full drains (one-time); seed A(1,1,kt=1) issue into SetA for r3(t=0).
  STG_B(0, 0, 0); STG_B(0, 1, 0);
  A_ISSUE(aA_, 0, 0);                // A(0,0) kt0
  A_ISSUE(aB_, 1, 0);                // A(0,1) kt0
  VMCNT0;
  A_WRITE(aA_, 0, 0); A_WRITE(aB_, 0, 1);
  A_ISSUE(aA_, 0, 1);                // A(1,0) kt1
  VMCNT0;
  A_WRITE(aA_, 1, 0);
  A_ISSUE(aA_, 1, 1);                // seed #1: A(1,1) kt1 -> SetA (consumed r3)
  LGKM0;
  SB0;
  __builtin_amdgcn_s_barrier();
  LA(0, 0, 0); LB(0, 0, 0); LA(0, 0, 1); LB(0, 0, 1);  // reads for region 1

  for (int t = 0; t < 31; ++t) {
    const int kt1 = 2 * t + 1;     // buf0 = kt1-1, buf1 = kt1
    REGION(0, 0, LB(0,1,0),            LB(0,1,1),
           STG_B(1,0,kt1),                                        NOOP);
    REGION(0, 1, LA(0,1,0),            LA(0,1,1),
           STG_B(1,1,kt1),                                        NOOP);
    REGION(1, 1, LB(0,0,0),            LB(0,0,1),
           A_WRITE(aA_,1,1); A_ISSUE(aB_,0,kt1+1),                VMCNT2);
    REGION(1, 0, LA(1,0,0); LB(1,0,0), LA(1,0,1); LB(1,0,1),
           STG_B(0,0,kt1+1),                                      VMCNT4);
    REGION(0, 0, LB(1,1,0),            LB(1,1,1),
           A_WRITE(aB_,0,0); A_ISSUE(aA_,1,kt1+1),                VMCNT2);
    REGION(0, 1, LA(1,1,0),            LA(1,1,1),
           STG_B(0,1,kt1+1); SB0; A_ISSUE(aB_,0,kt1+2),           NOOP);
    REGION(1, 1, LB(1,0,0),            LB(1,0,1),
           A_WRITE(aA_,0,1),                                      VMCNT6);
    REGION(1, 0, LA(0,0,0); LB(0,0,0), LA(0,0,1); LB(0,0,1),
           A_WRITE(aB_,1,0); A_ISSUE(aA_,1,kt1+2),                VMCNT0);
  }
  // peel: buf0 = kt62, buf1 = kt63; no OOB stages/issues.
  REGION(0, 0, LB(0,1,0),            LB(0,1,1),            STG_B(1,0,63), NOOP);
  REGION(0, 1, LA(0,1,0),            LA(0,1,1),            STG_B(1,1,63), NOOP);
  REGION(1, 1, LB(0,0,0),            LB(0,0,1),            A_WRITE(aA_,1,1), VMCNT2);
  REGION(1, 0, LA(1,0,0); LB(1,0,0), LA(1,0,1); LB(1,0,1), NOOP,          VMCNT0);
  REGION(0, 0, LB(1,1,0),            LB(1,1,1),            NOOP,          NOOP);
  REGION(0, 1, LA(1,1,0),            LA(1,1,1),            NOOP,          NOOP);
  REGION(1, 1, LB(1,0,0),            LB(1,0,1),            NOOP,          NOOP);
  REGION(1, 0, NOOP,                 NOOP,                 NOOP,          NOOP);

  // epilogue: C/D layout col=lane&15, row=(lane>>4)*4+j
#pragma unroll
  for (int qn = 0; qn < 2; ++qn)
#pragma unroll
    for (int nf = 0; nf < 2; ++nf) {
      int gcol = n0 + qn * 128 + wc * 32 + nf * 16 + (lane & 15);
      float bv = bias[gcol];
#pragma unroll
      for (int qm = 0; qm < 2; ++qm)
#pragma unroll
        for (int mf = 0; mf < 4; ++mf) {
          int grow = m0 + qm * 128 + wr * 64 + mf * 16 + ((lane >> 4) << 2);
          f32x4 v = acc[qm][qn][mf][nf];
#pragma unroll
          for (int j = 0; j < 4; ++j)
            C[(size_t)(grow + j) * N_DIM + gcol] = v[j] + bv;
        }
    }
}

extern "C" void kernel_launch(void* const* d_in, const int* in_sizes, int n_in,
                              void* d_out, int out_size, void* d_ws, size_t ws_size,
                              hipStream_t stream) {
  const float* x       = (const float*)d_in[0];
  const int*   qweight = (const int*)d_in[1];
  const float* scale   = (const float*)d_in[2];
  const float* zero    = (const float*)d_in[3];
  const float* bias    = (const float*)d_in[4];
  float* out = (float*)d_out;

  unsigned short* Wb = (unsigned short*)d_ws;                    // 32 MB

  prep_kernel<<<2048, 256, 0, stream>>>(qweight, scale, zero, Wb);
  gemm_kernel<<<(M_DIM / BM) * (N_DIM / BN), 512, 0, stream>>>(x, Wb, bias, out);
}

// Round 17
// 260.368 us; speedup vs baseline: 1.6692x; 1.5733x over previous
//
#include <hip/hip_runtime.h>
#include <hip/hip_bf16.h>
#include <stdint.h>

typedef __attribute__((ext_vector_type(8))) short short8;
typedef __attribute__((ext_vector_type(4))) float f32x4;

#define M_DIM 8192
#define N_DIM 4096
#define K_DIM 4096
#define BM 256
#define BN 256
#define BK 64

static __device__ __forceinline__ unsigned short f32_to_bf16(float f) {
  union { float f; unsigned int u; } v; v.f = f;
  unsigned int u = v.u;
  u += 0x7fffu + ((u >> 16) & 1u);   // round-to-nearest-even
  return (unsigned short)(u >> 16);
}

// ------- fused prep: blocks [0,16384) cast x->bf16; [16384,18432) dequant ----
// (validated R9/R11/R14; ~43us for 240MB of traffic)
// R15/R16 note: folding the x-cast into GEMM A-staging (dequant-only prep,
// ~10us) regressed the GEMM 212->430us both times (reg-staged A exposes
// vmcnt-drain serialization the gld_lds path avoids) — fusion abandoned.
__global__ void prep_kernel(const float* __restrict__ x,
                            unsigned short* __restrict__ xb,
                            const int* __restrict__ qw,
                            const float* __restrict__ scale,
                            const float* __restrict__ zero,
                            unsigned short* __restrict__ W) {
  if (blockIdx.x < 16384) {
    size_t i = ((size_t)blockIdx.x * blockDim.x + threadIdx.x) * 8;
    float4 v0 = *reinterpret_cast<const float4*>(x + i);
    float4 v1 = *reinterpret_cast<const float4*>(x + i + 4);
    short8 o;
    o[0] = (short)f32_to_bf16(v0.x);
    o[1] = (short)f32_to_bf16(v0.y);
    o[2] = (short)f32_to_bf16(v0.z);
    o[3] = (short)f32_to_bf16(v0.w);
    o[4] = (short)f32_to_bf16(v1.x);
    o[5] = (short)f32_to_bf16(v1.y);
    o[6] = (short)f32_to_bf16(v1.z);
    o[7] = (short)f32_to_bf16(v1.w);
    *reinterpret_cast<short8*>(xb + i) = o;
  } else {
    int idx = (blockIdx.x - 16384) * blockDim.x + threadIdx.x;   // n*128 + c
    int n = idx >> 7;
    int c = idx & 127;
    unsigned int w[8];
#pragma unroll
    for (int k = 0; k < 8; ++k)
      w[k] = (unsigned int)qw[(size_t)k * (N_DIM * 128) + idx];
    int wp = c >> 5, t = c & 31;
#pragma unroll
    for (int s = 0; s < 4; ++s) {
      int r = s ^ 3;
      unsigned int by[8];
#pragma unroll
      for (int k = 0; k < 8; ++k) by[k] = (w[k] >> (8 * r)) & 0xffu;
      int ibase = wp * 1024 + s * 256 + t * 8;
      int g = ibase >> 7;
      float sc = scale[n * 32 + g];
      float zp = zero[n * 32 + g] * 16.0f;
      short8 o;
#pragma unroll
      for (int u = 0; u < 8; ++u) {
        unsigned int q = 0;
#pragma unroll
        for (int k = 0; k < 8; ++k)
          q |= ((by[k] >> (7 - u)) & 1u) << (7 - k);
        o[u] = (short)f32_to_bf16(sc * ((float)q - zp));
      }
      *reinterpret_cast<short8*>(&W[(size_t)n * K_DIM + ibase]) = o;
    }
  }
}

// ---- 256x256 8-region bf16 GEMM — byte-exact R8/R11/R14 (verified: 212us,
// MfmaUtil 62%, 0 bank conflicts, absmax 1.0; matrix-busy ~= 132us MFMA floor) ----
// C[M][N] = A[M][K] * B[N][K]^T + bias. 8 waves (2Mx4N), wave out 128x64.
// Region p: bar; vmcnt(2); SB0; prio1; stage; kk0-MFMA(8); rd(p+1,kk0); SB0;
//           kk1-MFMA(8); rd(p+1,kk1); SB0; prio0.
// No explicit lgkmcnt(0) at entry — compiler emits precise counted lgkm
// waits before each consuming MFMA octet. Cross-wave visibility ledger:
// pair staged at region s -> all-waves drain (vmcnt after barrier) at
// s+1..s+2 entry -> read at >= s+3 (drain->barrier->read on every edge).
// Prologue drains buf0 (vmcnt(2)) + barrier BEFORE any cross-slot ds_read
// (R5 NaN lesson). Peel pulls the A(1,1,63) drain to p5 (vmcnt(0)).
// Structure-space notes (all HW-verified this session):
//  - R7 full reg-pingpong: -9%  - R9 quad-interleave: -3%
//  - R10 mfma 32x32x16: +2.9e7 bank conflicts, -9%
//  - R13 256x128/BK=32/2-blocks-per-CU: MfmaUtil 42%, -38%
//  - R15/R16 fused-A reg-staging: -65% (vmcnt-drain serialization)

#define VMCNT2 asm volatile("s_waitcnt vmcnt(2)" ::: "memory")
#define VMCNT0 asm volatile("s_waitcnt vmcnt(0)" ::: "memory")
#define NOOP ((void)0)
#define SB0 __builtin_amdgcn_sched_barrier(0)

#define STG(G, GROWB, KT, LDSC) do {                                           \
  const unsigned short* sb_ = (G) + ((size_t)(GROWB) * K_DIM + (KT) * 64);     \
  __builtin_amdgcn_global_load_lds(                                            \
      (const __attribute__((address_space(1))) void*)(sb_ + s_off0),           \
      (__attribute__((address_space(3))) void*)(smem + (LDSC) + wslot),        \
      16, 0, 0);                                                               \
  __builtin_amdgcn_global_load_lds(                                            \
      (const __attribute__((address_space(1))) void*)(sb_ + s_off1),           \
      (__attribute__((address_space(3))) void*)(smem + (LDSC) + 8192 + wslot), \
      16, 0, 0);                                                               \
} while (0)
#define STG_A(BUF, H, KT) STG(Ag, m0 + (H)*128, (KT), ((BUF)*2 + (H)) * 16384)
#define STG_B(BUF, H, KT) STG(Bg, n0 + (H)*128, (KT), 65536 + ((BUF)*2 + (H)) * 16384)

// reads for ONE k-slot (KK literal): 4 A-frags or 2 B-frags
#define LA(BUF, QM, KK) do {                                                   \
  _Pragma("unroll") for (int mf_ = 0; mf_ < 4; ++mf_)                          \
    a_[mf_][KK] = *(const short8*)(smem + ((KK) ? a_off1 : a_off0) +           \
        (((BUF)*2 + (QM)) * 16384 + mf_ * 2048));                              \
} while (0)
#define LB(BUF, QN, KK) do {                                                   \
  _Pragma("unroll") for (int nf_ = 0; nf_ < 2; ++nf_)                          \
    b_[nf_][KK] = *(const short8*)(smem + ((KK) ? b_off1 : b_off0) +           \
        (((BUF)*2 + (QN)) * 16384 + nf_ * 2048));                              \
} while (0)

#define MFMA_KK(QM, QN, KK)                                                    \
  _Pragma("unroll") for (int mf_ = 0; mf_ < 4; ++mf_)                          \
    _Pragma("unroll") for (int nf_ = 0; nf_ < 2; ++nf_)                        \
      acc[QM][QN][mf_][nf_] = __builtin_amdgcn_mfma_f32_16x16x32_bf16(         \
          a_[mf_][KK], b_[nf_][KK], acc[QM][QN][mf_][nf_], 0, 0, 0)

// one region; RD0/RD1 load operands for the NEXT region's MFMAs.
// WAR deps (RD0 overwrites [*][0] read by octet1) keep intra-region order.
#define REGION(QM, QN, RD0, RD1, STAGE, WAITV) do {                            \
  __builtin_amdgcn_s_barrier();                                                \
  WAITV;                                                                       \
  SB0;                                                                         \
  __builtin_amdgcn_s_setprio(1);                                               \
  STAGE;                                                                       \
  MFMA_KK(QM, QN, 0);                                                          \
  RD0;                                                                         \
  SB0;                                                                         \
  MFMA_KK(QM, QN, 1);                                                          \
  RD1;                                                                         \
  SB0;                                                                         \
  __builtin_amdgcn_s_setprio(0);                                               \
} while (0)

__global__ __launch_bounds__(512, 2) void gemm_kernel(
    const unsigned short* __restrict__ Ag,   // Xb [M][K] bf16
    const unsigned short* __restrict__ Bg,   // Wb [N][K] bf16
    const float* __restrict__ bias,
    float* __restrict__ C) {
  __shared__ __align__(16) char smem[131072];   // A: [0,64K), B: [64K,128K)

  // XCD-aware bijective swizzle: 512 blocks % 8 == 0
  int bid = blockIdx.x;
  int cpx = gridDim.x >> 3;
  int swz = (bid & 7) * cpx + (bid >> 3);
  int tm = swz >> 4;                 // 32 M-tiles
  int tn = swz & 15;                 // 16 N-tiles
  int m0 = tm * BM, n0 = tn * BN;

  int tid = threadIdx.x;
  int lane = tid & 63;
  int wid = tid >> 6;                // 8 waves
  int wr = wid >> 2, wc = wid & 3;   // 2 x 4

  // hoisted lane addressing (R4, validated)
  const int xorv = (lane & 7) << 4;
  const int hi4 = (lane >> 4) << 4;
  const int wrbase = wr * 64 + (lane & 15);
  const int wcbase = wc * 32 + (lane & 15);
  const int a_off0 = (wrbase << 7) + (hi4 ^ xorv);
  const int a_off1 = (wrbase << 7) + ((64 | hi4) ^ xorv);
  const int b_off0 = 65536 + (wcbase << 7) + (hi4 ^ xorv);
  const int b_off1 = 65536 + (wcbase << 7) + ((64 | hi4) ^ xorv);
  const int wslot = (tid >> 6) << 10;
  const int s_lr0 = tid >> 3, s_lr1 = 64 + (tid >> 3);
  const int s_off0 = s_lr0 * K_DIM + (((tid & 7) ^ (s_lr0 & 7)) << 3);
  const int s_off1 = s_lr1 * K_DIM + (((tid & 7) ^ (s_lr1 & 7)) << 3);

  short8 a_[4][2], b_[2][2];
  f32x4 acc[2][2][4][2];
#pragma unroll
  for (int i = 0; i < 2; ++i)
#pragma unroll
    for (int j = 0; j < 2; ++j)
#pragma unroll
      for (int mf = 0; mf < 4; ++mf)
#pragma unroll
        for (int nf = 0; nf < 2; ++nf) acc[i][j][mf][nf] = (f32x4){0.f, 0.f, 0.f, 0.f};

  // prologue: buf0 <- kt0 (B00,A00,B01,A01), buf1 A10 <- kt1.
  // vmcnt(2): ALL buf0 loads landed; barrier; then cross-slot ds_reads.
  STG_B(0, 0, 0); STG_A(0, 0, 0); STG_B(0, 1, 0); STG_A(0, 1, 0);
  STG_A(1, 0, 1);
  VMCNT2;
  __builtin_amdgcn_s_barrier();
  LA(0, 0, 0); LB(0, 0, 0); LA(0, 0, 1); LB(0, 0, 1);  // reads for region 1

  for (int t = 0; t < 31; ++t) {
    const int kt1 = 2 * t + 1;     // buf0 = kt1-1, buf1 = kt1
    REGION(0, 0, LB(0,1,0),            LB(0,1,1),            STG_B(1,0,kt1),   VMCNT2);
    REGION(0, 1, LA(0,1,0),            LA(0,1,1),            STG_B(1,1,kt1),   VMCNT2);
    REGION(1, 1, LB(0,0,0),            LB(0,0,1),            STG_A(1,1,kt1),   VMCNT2);
    REGION(1, 0, LA(1,0,0); LB(1,0,0), LA(1,0,1); LB(1,0,1), STG_B(0,0,kt1+1), VMCNT2);
    REGION(0, 0, LB(1,1,0),            LB(1,1,1),            STG_A(0,0,kt1+1), VMCNT2);
    REGION(0, 1, LA(1,1,0),            LA(1,1,1),            STG_B(0,1,kt1+1), VMCNT2);
    REGION(1, 1, LB(1,0,0),            LB(1,0,1),            STG_A(0,1,kt1+1), VMCNT2);
    REGION(1, 0, LA(0,0,0); LB(0,0,0), LA(0,0,1); LB(0,0,1), STG_A(1,0,kt1+2), VMCNT2);
  }
  // peeled final iteration: buf0 = 62, buf1 = 63; no OOB stages.
  // Drain of A11(63) pulled to p5 (vmcnt(0)) so p6's read is barrier-separated.
  REGION(0, 0, LB(0,1,0),            LB(0,1,1),            STG_B(1,0,63), VMCNT2);
  REGION(0, 1, LA(0,1,0),            LA(0,1,1),            STG_B(1,1,63), VMCNT2);
  REGION(1, 1, LB(0,0,0),            LB(0,0,1),            STG_A(1,1,63), VMCNT2);
  REGION(1, 0, LA(1,0,0); LB(1,0,0), LA(1,0,1); LB(1,0,1), NOOP,          VMCNT2);
  REGION(0, 0, LB(1,1,0),            LB(1,1,1),            NOOP,          VMCNT0);
  REGION(0, 1, LA(1,1,0),            LA(1,1,1),            NOOP,          NOOP);
  REGION(1, 1, LB(1,0,0),            LB(1,0,1),            NOOP,          NOOP);
  REGION(1, 0, NOOP,                 NOOP,                 NOOP,          NOOP);

  // epilogue: C/D layout col=lane&15, row=(lane>>4)*4+j
#pragma unroll
  for (int qn = 0; qn < 2; ++qn)
#pragma unroll
    for (int nf = 0; nf < 2; ++nf) {
      int gcol = n0 + qn * 128 + wc * 32 + nf * 16 + (lane & 15);
      float bv = bias[gcol];
#pragma unroll
      for (int qm = 0; qm < 2; ++qm)
#pragma unroll
        for (int mf = 0; mf < 4; ++mf) {
          int grow = m0 + qm * 128 + wr * 64 + mf * 16 + ((lane >> 4) << 2);
          f32x4 v = acc[qm][qn][mf][nf];
#pragma unroll
          for (int j = 0; j < 4; ++j)
            C[(size_t)(grow + j) * N_DIM + gcol] = v[j] + bv;
        }
    }
}

extern "C" void kernel_launch(void* const* d_in, const int* in_sizes, int n_in,
                              void* d_out, int out_size, void* d_ws, size_t ws_size,
                              hipStream_t stream) {
  const float* x       = (const float*)d_in[0];
  const int*   qweight = (const int*)d_in[1];
  const float* scale   = (const float*)d_in[2];
  const float* zero    = (const float*)d_in[3];
  const float* bias    = (const float*)d_in[4];
  float* out = (float*)d_out;

  unsigned short* Xb = (unsigned short*)d_ws;                    // 64 MB
  unsigned short* Wb = Xb + (size_t)M_DIM * K_DIM;               // 32 MB

  prep_kernel<<<16384 + 2048, 256, 0, stream>>>(x, Xb, qweight, scale, zero, Wb);
  gemm_kernel<<<(M_DIM / BM) * (N_DIM / BN), 512, 0, stream>>>(Xb, Wb, bias, out);
}

// Round 18
// 259.918 us; speedup vs baseline: 1.6721x; 1.0017x over previous
//
#include <hip/hip_runtime.h>
#include <hip/hip_bf16.h>
#include <stdint.h>

typedef __attribute__((ext_vector_type(8))) short short8;
typedef __attribute__((ext_vector_type(4))) float f32x4;

#define M_DIM 8192
#define N_DIM 4096
#define K_DIM 4096
#define BM 256
#define BN 256
#define BK 64

static __device__ __forceinline__ unsigned short f32_to_bf16(float f) {
  union { float f; unsigned int u; } v; v.f = f;
  unsigned int u = v.u;
  u += 0x7fffu + ((u >> 16) & 1u);   // round-to-nearest-even
  return (unsigned short)(u >> 16);
}

// ------- fused prep: blocks [0,16384) cast x->bf16; [16384,18432) dequant ----
// Verified at memory roofline: 272MB traffic / 6.3 TB/s = 43.2us computed,
// 43us measured. R15/R16: folding the cast into GEMM A-staging regressed the
// GEMM 212->430us both times (reg-staged A exposes vmcnt-drain serialization
// the gld_lds path avoids) — fusion abandoned.
__global__ void prep_kernel(const float* __restrict__ x,
                            unsigned short* __restrict__ xb,
                            const int* __restrict__ qw,
                            const float* __restrict__ scale,
                            const float* __restrict__ zero,
                            unsigned short* __restrict__ W) {
  if (blockIdx.x < 16384) {
    size_t i = ((size_t)blockIdx.x * blockDim.x + threadIdx.x) * 8;
    float4 v0 = *reinterpret_cast<const float4*>(x + i);
    float4 v1 = *reinterpret_cast<const float4*>(x + i + 4);
    short8 o;
    o[0] = (short)f32_to_bf16(v0.x);
    o[1] = (short)f32_to_bf16(v0.y);
    o[2] = (short)f32_to_bf16(v0.z);
    o[3] = (short)f32_to_bf16(v0.w);
    o[4] = (short)f32_to_bf16(v1.x);
    o[5] = (short)f32_to_bf16(v1.y);
    o[6] = (short)f32_to_bf16(v1.z);
    o[7] = (short)f32_to_bf16(v1.w);
    *reinterpret_cast<short8*>(xb + i) = o;
  } else {
    int idx = (blockIdx.x - 16384) * blockDim.x + threadIdx.x;   // n*128 + c
    int n = idx >> 7;
    int c = idx & 127;
    unsigned int w[8];
#pragma unroll
    for (int k = 0; k < 8; ++k)
      w[k] = (unsigned int)qw[(size_t)k * (N_DIM * 128) + idx];
    int wp = c >> 5, t = c & 31;
#pragma unroll
    for (int s = 0; s < 4; ++s) {
      int r = s ^ 3;
      unsigned int by[8];
#pragma unroll
      for (int k = 0; k < 8; ++k) by[k] = (w[k] >> (8 * r)) & 0xffu;
      int ibase = wp * 1024 + s * 256 + t * 8;
      int g = ibase >> 7;
      float sc = scale[n * 32 + g];
      float zp = zero[n * 32 + g] * 16.0f;
      short8 o;
#pragma unroll
      for (int u = 0; u < 8; ++u) {
        unsigned int q = 0;
#pragma unroll
        for (int k = 0; k < 8; ++k)
          q |= ((by[k] >> (7 - u)) & 1u) << (7 - k);
        o[u] = (short)f32_to_bf16(sc * ((float)q - zp));
      }
      *reinterpret_cast<short8*>(&W[(size_t)n * K_DIM + ibase]) = o;
    }
  }
}

// ---- 256x256 8-region bf16 GEMM — FINAL (verified 3x: 213-217us GEMM,
// MfmaUtil 60-62%, 0 bank conflicts, absmax 1.0) ----
// C[M][N] = A[M][K] * B[N][K]^T + bias. 8 waves (2Mx4N), wave out 128x64.
// Region p: bar; vmcnt(2); SB0; prio1; stage; kk0-MFMA(8); rd(p+1,kk0); SB0;
//           kk1-MFMA(8); rd(p+1,kk1); SB0; prio0.
// Matrix-busy (~133us) == MFMA floor (275 GFLOP / 2075 TF measured 16x16x32
// ceiling = 132us): the loop issues MFMAs at full hardware rate; residue is
// all-wave barrier convergence at 1 block/CU.
// Cross-wave visibility ledger: pair staged at region s -> all-waves drain
// (vmcnt after barrier) at s+1..s+2 entry -> read at >= s+3
// (drain->barrier->read on every edge). Prologue drains buf0 (vmcnt(2)) +
// barrier BEFORE any cross-slot ds_read (R5 NaN lesson). Peel pulls the
// A(1,1,63) drain to p5 (vmcnt(0)). SB0s are load-bearing: they pin next-
// region ds_reads AFTER the entry barrier+drain (removing them re-opens the
// R5-class race).
// Structure-space, all HW-verified this session:
//  - R7 full reg-pingpong: -9%  - R9 quad-interleave: -3%
//  - R10 mfma 32x32x16: +2.9e7 bank conflicts, -9%
//  - R13 256x128/BK=32/2-blocks-per-CU: MfmaUtil 42%, -38%
//  - R15/R16 fused-A reg-staging: -65% (vmcnt-drain serialization)
//  - deeper pipelining: needs >256 unified regs/wave (248 used); 3-buf needs
//    >160KB LDS — both hard limits.

#define VMCNT2 asm volatile("s_waitcnt vmcnt(2)" ::: "memory")
#define VMCNT0 asm volatile("s_waitcnt vmcnt(0)" ::: "memory")
#define NOOP ((void)0)
#define SB0 __builtin_amdgcn_sched_barrier(0)

#define STG(G, GROWB, KT, LDSC) do {                                           \
  const unsigned short* sb_ = (G) + ((size_t)(GROWB) * K_DIM + (KT) * 64);     \
  __builtin_amdgcn_global_load_lds(                                            \
      (const __attribute__((address_space(1))) void*)(sb_ + s_off0),           \
      (__attribute__((address_space(3))) void*)(smem + (LDSC) + wslot),        \
      16, 0, 0);                                                               \
  __builtin_amdgcn_global_load_lds(                                            \
      (const __attribute__((address_space(1))) void*)(sb_ + s_off1),           \
      (__attribute__((address_space(3))) void*)(smem + (LDSC) + 8192 + wslot), \
      16, 0, 0);                                                               \
} while (0)
#define STG_A(BUF, H, KT) STG(Ag, m0 + (H)*128, (KT), ((BUF)*2 + (H)) * 16384)
#define STG_B(BUF, H, KT) STG(Bg, n0 + (H)*128, (KT), 65536 + ((BUF)*2 + (H)) * 16384)

// reads for ONE k-slot (KK literal): 4 A-frags or 2 B-frags
#define LA(BUF, QM, KK) do {                                                   \
  _Pragma("unroll") for (int mf_ = 0; mf_ < 4; ++mf_)                          \
    a_[mf_][KK] = *(const short8*)(smem + ((KK) ? a_off1 : a_off0) +           \
        (((BUF)*2 + (QM)) * 16384 + mf_ * 2048));                              \
} while (0)
#define LB(BUF, QN, KK) do {                                                   \
  _Pragma("unroll") for (int nf_ = 0; nf_ < 2; ++nf_)                          \
    b_[nf_][KK] = *(const short8*)(smem + ((KK) ? b_off1 : b_off0) +           \
        (((BUF)*2 + (QN)) * 16384 + nf_ * 2048));                              \
} while (0)

#define MFMA_KK(QM, QN, KK)                                                    \
  _Pragma("unroll") for (int mf_ = 0; mf_ < 4; ++mf_)                          \
    _Pragma("unroll") for (int nf_ = 0; nf_ < 2; ++nf_)                        \
      acc[QM][QN][mf_][nf_] = __builtin_amdgcn_mfma_f32_16x16x32_bf16(         \
          a_[mf_][KK], b_[nf_][KK], acc[QM][QN][mf_][nf_], 0, 0, 0)

// one region; RD0/RD1 load operands for the NEXT region's MFMAs.
// WAR deps (RD0 overwrites [*][0] read by octet1) keep intra-region order.
#define REGION(QM, QN, RD0, RD1, STAGE, WAITV) do {                            \
  __builtin_amdgcn_s_barrier();                                                \
  WAITV;                                                                       \
  SB0;                                                                         \
  __builtin_amdgcn_s_setprio(1);                                               \
  STAGE;                                                                       \
  MFMA_KK(QM, QN, 0);                                                          \
  RD0;                                                                         \
  SB0;                                                                         \
  MFMA_KK(QM, QN, 1);                                                          \
  RD1;                                                                         \
  SB0;                                                                         \
  __builtin_amdgcn_s_setprio(0);                                               \
} while (0)

__global__ __launch_bounds__(512, 2) void gemm_kernel(
    const unsigned short* __restrict__ Ag,   // Xb [M][K] bf16
    const unsigned short* __restrict__ Bg,   // Wb [N][K] bf16
    const float* __restrict__ bias,
    float* __restrict__ C) {
  __shared__ __align__(16) char smem[131072];   // A: [0,64K), B: [64K,128K)

  // XCD-aware bijective swizzle: 512 blocks % 8 == 0
  int bid = blockIdx.x;
  int cpx = gridDim.x >> 3;
  int swz = (bid & 7) * cpx + (bid >> 3);
  int tm = swz >> 4;                 // 32 M-tiles
  int tn = swz & 15;                 // 16 N-tiles
  int m0 = tm * BM, n0 = tn * BN;

  int tid = threadIdx.x;
  int lane = tid & 63;
  int wid = tid >> 6;                // 8 waves
  int wr = wid >> 2, wc = wid & 3;   // 2 x 4

  // hoisted lane addressing (R4, validated)
  const int xorv = (lane & 7) << 4;
  const int hi4 = (lane >> 4) << 4;
  const int wrbase = wr * 64 + (lane & 15);
  const int wcbase = wc * 32 + (lane & 15);
  const int a_off0 = (wrbase << 7) + (hi4 ^ xorv);
  const int a_off1 = (wrbase << 7) + ((64 | hi4) ^ xorv);
  const int b_off0 = 65536 + (wcbase << 7) + (hi4 ^ xorv);
  const int b_off1 = 65536 + (wcbase << 7) + ((64 | hi4) ^ xorv);
  const int wslot = (tid >> 6) << 10;
  const int s_lr0 = tid >> 3, s_lr1 = 64 + (tid >> 3);
  const int s_off0 = s_lr0 * K_DIM + (((tid & 7) ^ (s_lr0 & 7)) << 3);
  const int s_off1 = s_lr1 * K_DIM + (((tid & 7) ^ (s_lr1 & 7)) << 3);

  short8 a_[4][2], b_[2][2];
  f32x4 acc[2][2][4][2];
#pragma unroll
  for (int i = 0; i < 2; ++i)
#pragma unroll
    for (int j = 0; j < 2; ++j)
#pragma unroll
      for (int mf = 0; mf < 4; ++mf)
#pragma unroll
        for (int nf = 0; nf < 2; ++nf) acc[i][j][mf][nf] = (f32x4){0.f, 0.f, 0.f, 0.f};

  // prologue: buf0 <- kt0 (B00,A00,B01,A01), buf1 A10 <- kt1.
  // vmcnt(2): ALL buf0 loads landed; barrier; then cross-slot ds_reads.
  STG_B(0, 0, 0); STG_A(0, 0, 0); STG_B(0, 1, 0); STG_A(0, 1, 0);
  STG_A(1, 0, 1);
  VMCNT2;
  __builtin_amdgcn_s_barrier();
  LA(0, 0, 0); LB(0, 0, 0); LA(0, 0, 1); LB(0, 0, 1);  // reads for region 1

  for (int t = 0; t < 31; ++t) {
    const int kt1 = 2 * t + 1;     // buf0 = kt1-1, buf1 = kt1
    REGION(0, 0, LB(0,1,0),            LB(0,1,1),            STG_B(1,0,kt1),   VMCNT2);
    REGION(0, 1, LA(0,1,0),            LA(0,1,1),            STG_B(1,1,kt1),   VMCNT2);
    REGION(1, 1, LB(0,0,0),            LB(0,0,1),            STG_A(1,1,kt1),   VMCNT2);
    REGION(1, 0, LA(1,0,0); LB(1,0,0), LA(1,0,1); LB(1,0,1), STG_B(0,0,kt1+1), VMCNT2);
    REGION(0, 0, LB(1,1,0),            LB(1,1,1),            STG_A(0,0,kt1+1), VMCNT2);
    REGION(0, 1, LA(1,1,0),            LA(1,1,1),            STG_B(0,1,kt1+1), VMCNT2);
    REGION(1, 1, LB(1,0,0),            LB(1,0,1),            STG_A(0,1,kt1+1), VMCNT2);
    REGION(1, 0, LA(0,0,0); LB(0,0,0), LA(0,0,1); LB(0,0,1), STG_A(1,0,kt1+2), VMCNT2);
  }
  // peeled final iteration: buf0 = 62, buf1 = 63; no OOB stages.
  // Drain of A11(63) pulled to p5 (vmcnt(0)) so p6's read is barrier-separated.
  REGION(0, 0, LB(0,1,0),            LB(0,1,1),            STG_B(1,0,63), VMCNT2);
  REGION(0, 1, LA(0,1,0),            LA(0,1,1),            STG_B(1,1,63), VMCNT2);
  REGION(1, 1, LB(0,0,0),            LB(0,0,1),            STG_A(1,1,63), VMCNT2);
  REGION(1, 0, LA(1,0,0); LB(1,0,0), LA(1,0,1); LB(1,0,1), NOOP,          VMCNT2);
  REGION(0, 0, LB(1,1,0),            LB(1,1,1),            NOOP,          VMCNT0);
  REGION(0, 1, LA(1,1,0),            LA(1,1,1),            NOOP,          NOOP);
  REGION(1, 1, LB(1,0,0),            LB(1,0,1),            NOOP,          NOOP);
  REGION(1, 0, NOOP,                 NOOP,                 NOOP,          NOOP);

  // epilogue: C/D layout col=lane&15, row=(lane>>4)*4+j
#pragma unroll
  for (int qn = 0; qn < 2; ++qn)
#pragma unroll
    for (int nf = 0; nf < 2; ++nf) {
      int gcol = n0 + qn * 128 + wc * 32 + nf * 16 + (lane & 15);
      float bv = bias[gcol];
#pragma unroll
      for (int qm = 0; qm < 2; ++qm)
#pragma unroll
        for (int mf = 0; mf < 4; ++mf) {
          int grow = m0 + qm * 128 + wr * 64 + mf * 16 + ((lane >> 4) << 2);
          f32x4 v = acc[qm][qn][mf][nf];
#pragma unroll
          for (int j = 0; j < 4; ++j)
            C[(size_t)(grow + j) * N_DIM + gcol] = v[j] + bv;
        }
    }
}

extern "C" void kernel_launch(void* const* d_in, const int* in_sizes, int n_in,
                              void* d_out, int out_size, void* d_ws, size_t ws_size,
                              hipStream_t stream) {
  const float* x       = (const float*)d_in[0];
  const int*   qweight = (const int*)d_in[1];
  const float* scale   = (const float*)d_in[2];
  const float* zero    = (const float*)d_in[3];
  const float* bias    = (const float*)d_in[4];
  float* out = (float*)d_out;

  unsigned short* Xb = (unsigned short*)d_ws;                    // 64 MB
  unsigned short* Wb = Xb + (size_t)M_DIM * K_DIM;               // 32 MB

  prep_kernel<<<16384 + 2048, 256, 0, stream>>>(x, Xb, qweight, scale, zero, Wb);
  gemm_kernel<<<(M_DIM / BM) * (N_DIM / BN), 512, 0, stream>>>(Xb, Wb, bias, out);
}